// Round 5
// baseline (264.563 us; speedup 1.0000x reference)
//
#include <hip/hip_runtime.h>
#include <math.h>

#define NN 1024
#define CC 256
#define TT 64

typedef __attribute__((ext_vector_type(8))) short bf16x8;  // 8 bf16 (4 VGPRs)
typedef __attribute__((ext_vector_type(4))) float f32x4;   // MFMA accumulator

// round-to-nearest-even fp32 -> bf16 bits
__device__ __forceinline__ ushort f2bf(float f) {
  unsigned u = __float_as_uint(f);
  return (ushort)((u + 0x7fffu + ((u >> 16) & 1u)) >> 16);
}
__device__ __forceinline__ float bf2f(ushort b) {
  return __uint_as_float(((unsigned)b) << 16);
}

// ---------------- kernel 1: time-mean + norms + bf16 hi/lo split ----------------
// 2048 blocks x 1024 threads (16 waves). Block b -> tensor (b>>10), row (b&1023).
// Each thread: 4 independent float4 loads (16 VGPRs -- always kept in flight),
// LDS tree across the 16 waves. 32k waves total = copy-kernel regime.
__global__ __launch_bounds__(1024) void mean_norm_kernel(
    const float* __restrict__ in0, const float* __restrict__ in1,
    ushort* __restrict__ xh, ushort* __restrict__ xl,
    ushort* __restrict__ yh, ushort* __restrict__ yl,
    float* __restrict__ nx, float* __restrict__ ny,
    float* __restrict__ Rx, float* __restrict__ Ry,
    float* __restrict__ sums, unsigned* __restrict__ counter) {
  int b = blockIdx.x;
  int tid = threadIdx.x;

  // init duties for the fused dist+finalize kernel (runs strictly later)
  if (b == 0) Rx[tid] = 0.f;
  else if (b == 1) Ry[tid] = 0.f;
  else if (b == 2) { if (tid < 3) sums[tid] = 0.f; if (tid == 3) *counter = 0u; }

  int m = b >> 10;
  int n = b & (NN - 1);
  int c4 = tid & 63;            // float4 channel index (64 per row)
  int tq = tid >> 6;            // wave id = time-16th (0..15)
  const float4* src = (const float4*)((m ? in1 : in0) + (size_t)n * (TT * CC)) + c4;

  float4 v0 = src[(tq * 4 + 0) * (CC / 4)];
  float4 v1 = src[(tq * 4 + 1) * (CC / 4)];
  float4 v2 = src[(tq * 4 + 2) * (CC / 4)];
  float4 v3 = src[(tq * 4 + 3) * (CC / 4)];
  float4 s;
  s.x = (v0.x + v1.x) + (v2.x + v3.x);
  s.y = (v0.y + v1.y) + (v2.y + v3.y);
  s.z = (v0.z + v1.z) + (v2.z + v3.z);
  s.w = (v0.w + v1.w) + (v2.w + v3.w);

  __shared__ float4 red[16][64];
  red[tq][c4] = s;
  __syncthreads();

  if (tid < 64) {
    float4 acc = red[0][tid];
    #pragma unroll
    for (int i = 1; i < 16; ++i) {
      float4 t = red[i][tid];
      acc.x += t.x; acc.y += t.y; acc.z += t.z; acc.w += t.w;
    }
    const float inv = 1.0f / TT;
    acc.x *= inv; acc.y *= inv; acc.z *= inv; acc.w *= inv;

    ushort* ho = m ? yh : xh;
    ushort* lo = m ? yl : xl;
    ushort4 h4, l4;
    h4.x = f2bf(acc.x); l4.x = f2bf(acc.x - bf2f(h4.x));
    h4.y = f2bf(acc.y); l4.y = f2bf(acc.y - bf2f(h4.y));
    h4.z = f2bf(acc.z); l4.z = f2bf(acc.z - bf2f(h4.z));
    h4.w = f2bf(acc.w); l4.w = f2bf(acc.w - bf2f(h4.w));
    ((ushort4*)(ho + (size_t)n * CC))[tid] = h4;
    ((ushort4*)(lo + (size_t)n * CC))[tid] = l4;

    float ssq = fmaf(acc.x, acc.x, fmaf(acc.y, acc.y, fmaf(acc.z, acc.z, acc.w * acc.w)));
    #pragma unroll
    for (int o = 32; o > 0; o >>= 1) ssq += __shfl_down(ssq, o, 64);
    if (tid == 0) (m ? ny : nx)[n] = ssq;
  }
}

// ---------------- kernel 2: MFMA gram + distance epilogue + last-block finalize ----
// Grid (32,32) = 1024 blocks (4/CU, 16 waves/CU). 32x32 tile, 4 waves, wave w ->
// 16x16 quadrant (wr=w>>1, wc=w&1). Per wave per K-step: 8x16B global loads
// (L2-resident) + 6 bf16 MFMAs (hi/lo 3-term split, x and y). No LDS in K-loop.
__global__ __launch_bounds__(256) void dist_kernel(
    const ushort* __restrict__ xh, const ushort* __restrict__ xl,
    const ushort* __restrict__ yh, const ushort* __restrict__ yl,
    const float* __restrict__ nx, const float* __restrict__ ny,
    float* __restrict__ Rx, float* __restrict__ Ry,
    float* __restrict__ sums, unsigned* __restrict__ counter,
    float* __restrict__ out) {
  int tid = threadIdx.x;
  int lane = tid & 63;
  int w = tid >> 6;
  int wr = w >> 1, wc = w & 1;
  int col = lane & 15, quad = lane >> 4;

  int ti = blockIdx.y * 32, tj = blockIdx.x * 32;
  int aRow = ti + wr * 16 + col;   // A operand: m = lane&15
  int bRow = tj + wc * 16 + col;   // B operand: n = lane&15

  f32x4 accx = {};
  f32x4 accy = {};

  #pragma unroll 2
  for (int k0 = 0; k0 < CC; k0 += 32) {
    int kk = k0 + quad * 8;
    size_t ao = (size_t)aRow * CC + kk;
    size_t bo = (size_t)bRow * CC + kk;
    bf16x8 Ahx = *(const bf16x8*)(xh + ao);
    bf16x8 Alx = *(const bf16x8*)(xl + ao);
    bf16x8 Ahy = *(const bf16x8*)(yh + ao);
    bf16x8 Aly = *(const bf16x8*)(yl + ao);
    bf16x8 Bhx = *(const bf16x8*)(xh + bo);
    bf16x8 Blx = *(const bf16x8*)(xl + bo);
    bf16x8 Bhy = *(const bf16x8*)(yh + bo);
    bf16x8 Bly = *(const bf16x8*)(yl + bo);
    accx = __builtin_amdgcn_mfma_f32_16x16x32_bf16(Ahx, Bhx, accx, 0, 0, 0);
    accx = __builtin_amdgcn_mfma_f32_16x16x32_bf16(Ahx, Blx, accx, 0, 0, 0);
    accx = __builtin_amdgcn_mfma_f32_16x16x32_bf16(Alx, Bhx, accx, 0, 0, 0);
    accy = __builtin_amdgcn_mfma_f32_16x16x32_bf16(Ahy, Bhy, accy, 0, 0, 0);
    accy = __builtin_amdgcn_mfma_f32_16x16x32_bf16(Ahy, Bly, accy, 0, 0, 0);
    accy = __builtin_amdgcn_mfma_f32_16x16x32_bf16(Aly, Bhy, accy, 0, 0, 0);
  }

  // epilogue: d = sqrt(max(ni+nj-2g,0)+1e-12); row sums + product sums
  int rowBase = ti + wr * 16 + quad * 4;     // + r
  int colIdx  = tj + wc * 16 + col;
  float njxv = nx[colIdx], njyv = ny[colIdx];

  float ab = 0.f, aa = 0.f, bb = 0.f;
  #pragma unroll
  for (int r = 0; r < 4; ++r) {
    int grow = rowBase + r;
    float nix = nx[grow], niy = ny[grow];
    float dxv = sqrtf(fmaxf(nix + njxv - 2.f * accx[r], 0.f) + 1e-12f);
    float dyv = sqrtf(fmaxf(niy + njyv - 2.f * accy[r], 0.f) + 1e-12f);
    ab = fmaf(dxv, dyv, ab); aa = fmaf(dxv, dxv, aa); bb = fmaf(dyv, dyv, bb);
    float rsx = dxv, rsy = dyv;
    #pragma unroll
    for (int o = 8; o > 0; o >>= 1) {
      rsx += __shfl_down(rsx, o, 16);
      rsy += __shfl_down(rsy, o, 16);
    }
    if (col == 0) { atomicAdd(&Rx[grow], rsx); atomicAdd(&Ry[grow], rsy); }
  }

  #pragma unroll
  for (int o = 32; o > 0; o >>= 1) {
    ab += __shfl_down(ab, o, 64);
    aa += __shfl_down(aa, o, 64);
    bb += __shfl_down(bb, o, 64);
  }
  __shared__ float redp[3][4];
  if (lane == 0) { redp[0][w] = ab; redp[1][w] = aa; redp[2][w] = bb; }
  __syncthreads();
  if (tid == 0) {
    atomicAdd(&sums[0], redp[0][0] + redp[0][1] + redp[0][2] + redp[0][3]);
    atomicAdd(&sums[1], redp[1][0] + redp[1][1] + redp[1][2] + redp[1][3]);
    atomicAdd(&sums[2], redp[2][0] + redp[2][1] + redp[2][2] + redp[2][3]);
  }

  // -------- last block finalizes (all cross-block data via device-scope atomics) --
  __threadfence();
  __shared__ unsigned done;
  if (tid == 0) done = atomicAdd(counter, 1u);
  __syncthreads();
  if (done != 1023) return;

  double sx = 0, sy = 0, srr = 0, sxx = 0, syy = 0;
  #pragma unroll
  for (int i = 0; i < 4; ++i) {
    int row = tid * 4 + i;
    double rx = (double)atomicAdd(&Rx[row], 0.0f);   // coherent read
    double ry = (double)atomicAdd(&Ry[row], 0.0f);
    sx += rx; sy += ry; srr += rx * ry; sxx += rx * rx; syy += ry * ry;
  }
  #pragma unroll
  for (int o = 32; o > 0; o >>= 1) {
    sx += __shfl_down(sx, o, 64);  sy += __shfl_down(sy, o, 64);
    srr += __shfl_down(srr, o, 64); sxx += __shfl_down(sxx, o, 64);
    syy += __shfl_down(syy, o, 64);
  }
  __shared__ double td[5][4];
  if (lane == 0) { td[0][w] = sx; td[1][w] = sy; td[2][w] = srr; td[3][w] = sxx; td[4][w] = syy; }
  __syncthreads();
  if (tid == 0) {
    sx  = td[0][0] + td[0][1] + td[0][2] + td[0][3];
    sy  = td[1][0] + td[1][1] + td[1][2] + td[1][3];
    srr = td[2][0] + td[2][1] + td[2][2] + td[2][3];
    sxx = td[3][0] + td[3][1] + td[3][2] + td[3][3];
    syy = td[4][0] + td[4][1] + td[4][2] + td[4][3];
    double abt = (double)atomicAdd(&sums[0], 0.0f);
    double aat = (double)atomicAdd(&sums[1], 0.0f);
    double bbt = (double)atomicAdd(&sums[2], 0.0f);
    const double n = (double)NN, n2 = n * n;
    double AB = abt - (2.0 / n) * srr + sx * sy / n2;
    double AA = aat - (2.0 / n) * sxx + sx * sx / n2;
    double BB = bbt - (2.0 / n) * syy + sy * sy / n2;
    double xy = AB / n2, xx = AA / n2, yy = BB / n2;
    double r = xy / sqrt(xx * yy + 1e-9);
    out[0] = (float)(1.0 - r);
  }
}

extern "C" void kernel_launch(void* const* d_in, const int* in_sizes, int n_in,
                              void* d_out, int out_size, void* d_ws, size_t ws_size,
                              hipStream_t stream) {
  const float* in0 = (const float*)d_in[0];   // output_1 (N,T,C) fp32
  const float* in1 = (const float*)d_in[1];   // feature  (N,T,C) fp32

  char* ws = (char*)d_ws;
  const size_t SZ = (size_t)NN * CC * sizeof(ushort);     // 512 KB per bf16 array
  ushort* xh = (ushort*)(ws);
  ushort* xl = (ushort*)(ws + SZ);
  ushort* yh = (ushort*)(ws + 2 * SZ);
  ushort* yl = (ushort*)(ws + 3 * SZ);
  float* nx  = (float*)(ws + 4 * SZ);                      // 4 KB
  float* ny  = (float*)(ws + 4 * SZ + 4096);               // 4 KB
  float* Rx  = (float*)(ws + 4 * SZ + 8192);               // 4 KB (zeroed)
  float* Ry  = (float*)(ws + 4 * SZ + 12288);              // 4 KB (zeroed)
  float* sums = (float*)(ws + 4 * SZ + 16384);             // 3 floats (zeroed)
  unsigned* counter = (unsigned*)(ws + 4 * SZ + 16384 + 64); // 1 uint (zeroed)

  mean_norm_kernel<<<2 * NN, 1024, 0, stream>>>(in0, in1, xh, xl, yh, yl, nx, ny,
                                                Rx, Ry, sums, counter);
  dist_kernel<<<dim3(32, 32), 256, 0, stream>>>(xh, xl, yh, yl, nx, ny,
                                                Rx, Ry, sums, counter, (float*)d_out);
}

// Round 6
// 223.095 us; speedup vs baseline: 1.1859x; 1.1859x over previous
//
#include <hip/hip_runtime.h>
#include <math.h>

#define NN 1024
#define CC 256
#define TT 64

typedef __attribute__((ext_vector_type(8))) short bf16x8;  // 8 bf16 (4 VGPRs)
typedef __attribute__((ext_vector_type(4))) float f32x4;   // MFMA accumulator

// round-to-nearest-even fp32 -> bf16 bits
__device__ __forceinline__ ushort f2bf(float f) {
  unsigned u = __float_as_uint(f);
  return (ushort)((u + 0x7fffu + ((u >> 16) & 1u)) >> 16);
}
__device__ __forceinline__ float bf2f(ushort b) {
  return __uint_as_float(((unsigned)b) << 16);
}

// ---------------- kernel 1: time-mean + norms + bf16 hi/lo split ----------------
// 2048 blocks x 1024 threads (16 waves). Block b -> tensor (b>>10), row (b&1023).
// Each thread: 4 independent float4 loads, LDS tree across the 16 waves.
__global__ __launch_bounds__(1024) void mean_norm_kernel(
    const float* __restrict__ in0, const float* __restrict__ in1,
    ushort* __restrict__ xh, ushort* __restrict__ xl,
    ushort* __restrict__ yh, ushort* __restrict__ yl,
    float* __restrict__ nx, float* __restrict__ ny,
    float* __restrict__ Rx, float* __restrict__ Ry,
    float* __restrict__ sums, unsigned* __restrict__ counter) {
  int b = blockIdx.x;
  int tid = threadIdx.x;

  // init duties for the fused dist+finalize kernel (runs strictly later)
  if (b == 0) Rx[tid] = 0.f;
  else if (b == 1) Ry[tid] = 0.f;
  else if (b == 2) { if (tid < 3) sums[tid] = 0.f; if (tid == 3) *counter = 0u; }

  int m = b >> 10;
  int n = b & (NN - 1);
  int c4 = tid & 63;            // float4 channel index (64 per row)
  int tq = tid >> 6;            // wave id = time-16th (0..15)
  const float4* src = (const float4*)((m ? in1 : in0) + (size_t)n * (TT * CC)) + c4;

  float4 v0 = src[(tq * 4 + 0) * (CC / 4)];
  float4 v1 = src[(tq * 4 + 1) * (CC / 4)];
  float4 v2 = src[(tq * 4 + 2) * (CC / 4)];
  float4 v3 = src[(tq * 4 + 3) * (CC / 4)];
  float4 s;
  s.x = (v0.x + v1.x) + (v2.x + v3.x);
  s.y = (v0.y + v1.y) + (v2.y + v3.y);
  s.z = (v0.z + v1.z) + (v2.z + v3.z);
  s.w = (v0.w + v1.w) + (v2.w + v3.w);

  __shared__ float4 red[16][64];
  red[tq][c4] = s;
  __syncthreads();

  if (tid < 64) {
    float4 acc = red[0][tid];
    #pragma unroll
    for (int i = 1; i < 16; ++i) {
      float4 t = red[i][tid];
      acc.x += t.x; acc.y += t.y; acc.z += t.z; acc.w += t.w;
    }
    const float inv = 1.0f / TT;
    acc.x *= inv; acc.y *= inv; acc.z *= inv; acc.w *= inv;

    ushort* ho = m ? yh : xh;
    ushort* lo = m ? yl : xl;
    ushort4 h4, l4;
    h4.x = f2bf(acc.x); l4.x = f2bf(acc.x - bf2f(h4.x));
    h4.y = f2bf(acc.y); l4.y = f2bf(acc.y - bf2f(h4.y));
    h4.z = f2bf(acc.z); l4.z = f2bf(acc.z - bf2f(h4.z));
    h4.w = f2bf(acc.w); l4.w = f2bf(acc.w - bf2f(h4.w));
    ((ushort4*)(ho + (size_t)n * CC))[tid] = h4;
    ((ushort4*)(lo + (size_t)n * CC))[tid] = l4;

    float ssq = fmaf(acc.x, acc.x, fmaf(acc.y, acc.y, fmaf(acc.z, acc.z, acc.w * acc.w)));
    #pragma unroll
    for (int o = 32; o > 0; o >>= 1) ssq += __shfl_down(ssq, o, 64);
    if (tid == 0) (m ? ny : nx)[n] = ssq;
  }
}

// ---------------- kernel 2: LDS-staged MFMA gram + epilogue + last-block finalize --
// Grid 16x16 = 256 blocks x 1024 threads (16 waves = 4/SIMD, ~1 block/CU).
// 64x64 tile; wave w=(wr*4+wc) computes the 16x16 MFMA tile (wr,wc).
// Per K-step (32 ch): stage 8 tiles (A,B x {xh,xl,yh,yl}; 64 rows x 32 ch,
// row stride 80 B) via register-prefetched global loads + ds_write_b128;
// then 8 ds_read_b128 + 6 MFMAs per wave. K-loop never touches global.
#define RSTRIDE 80            // LDS tile row stride (bytes): breaks bank patterns
#define TILESZ  (64 * RSTRIDE)  // 5120 B per staged tile
__global__ __launch_bounds__(1024, 4) void dist_kernel(
    const ushort* __restrict__ xh, const ushort* __restrict__ xl,
    const ushort* __restrict__ yh, const ushort* __restrict__ yl,
    const float* __restrict__ nx, const float* __restrict__ ny,
    float* __restrict__ Rx, float* __restrict__ Ry,
    float* __restrict__ sums, unsigned* __restrict__ counter,
    float* __restrict__ out) {
  __shared__ char smem[8 * TILESZ];            // 40 KB staged tiles
  __shared__ float redR[2][4][64];             // row-sum partials [x/y][wc][row]
  __shared__ float redp[3][16];                // ab/aa/bb per wave
  __shared__ unsigned done;

  int tid = threadIdx.x;
  int lane = tid & 63;
  int w = tid >> 6;            // wave 0..15
  int wr = w >> 2, wc = w & 3;
  int col = lane & 15, quad = lane >> 4;

  int ti = blockIdx.y * 64, tj = blockIdx.x * 64;

  // ---- staging assignment: tile = tid>>7, two 16B chunks u and u+128 ----
  int tileIdx = tid >> 7;              // 0..7
  int u = tid & 127;
  const ushort* arrs[4] = {xh, xl, yh, yl};
  const ushort* arr = arrs[tileIdx & 3];
  int rbase = (tileIdx < 4) ? ti : tj;
  int row0 = u >> 2, ch16 = u & 3;     // chunk 0: row0, chunk 1: row0+32
  const ushort* gp0 = arr + (size_t)(rbase + row0) * CC + ch16 * 8;
  const ushort* gp1 = gp0 + (size_t)32 * CC;
  int lo0 = tileIdx * TILESZ + row0 * RSTRIDE + ch16 * 16;
  int lo1 = lo0 + 32 * RSTRIDE;

  // ---- fragment read offsets (fixed) ----
  int aoff = (wr * 16 + col) * RSTRIDE + quad * 16;
  int boff = (wc * 16 + col) * RSTRIDE + quad * 16;

  f32x4 accx = {};
  f32x4 accy = {};

  bf16x8 st0 = *(const bf16x8*)gp0;
  bf16x8 st1 = *(const bf16x8*)gp1;

  for (int ks = 0; ks < 8; ++ks) {
    if (ks) __syncthreads();                   // previous compute done
    *(bf16x8*)(smem + lo0) = st0;
    *(bf16x8*)(smem + lo1) = st1;
    if (ks < 7) {                              // prefetch next chunk (uniform branch)
      gp0 += 32; gp1 += 32;
      st0 = *(const bf16x8*)gp0;
      st1 = *(const bf16x8*)gp1;
    }
    __syncthreads();
    bf16x8 Ahx = *(const bf16x8*)(smem + 0 * TILESZ + aoff);
    bf16x8 Alx = *(const bf16x8*)(smem + 1 * TILESZ + aoff);
    bf16x8 Ahy = *(const bf16x8*)(smem + 2 * TILESZ + aoff);
    bf16x8 Aly = *(const bf16x8*)(smem + 3 * TILESZ + aoff);
    bf16x8 Bhx = *(const bf16x8*)(smem + 4 * TILESZ + boff);
    bf16x8 Blx = *(const bf16x8*)(smem + 5 * TILESZ + boff);
    bf16x8 Bhy = *(const bf16x8*)(smem + 6 * TILESZ + boff);
    bf16x8 Bly = *(const bf16x8*)(smem + 7 * TILESZ + boff);
    accx = __builtin_amdgcn_mfma_f32_16x16x32_bf16(Ahx, Bhx, accx, 0, 0, 0);
    accx = __builtin_amdgcn_mfma_f32_16x16x32_bf16(Ahx, Blx, accx, 0, 0, 0);
    accx = __builtin_amdgcn_mfma_f32_16x16x32_bf16(Alx, Bhx, accx, 0, 0, 0);
    accy = __builtin_amdgcn_mfma_f32_16x16x32_bf16(Ahy, Bhy, accy, 0, 0, 0);
    accy = __builtin_amdgcn_mfma_f32_16x16x32_bf16(Ahy, Bly, accy, 0, 0, 0);
    accy = __builtin_amdgcn_mfma_f32_16x16x32_bf16(Aly, Bhy, accy, 0, 0, 0);
  }

  // ---- epilogue: d = sqrt(max(ni+nj-2g,0)+1e-12); sums ----
  int colIdx = tj + wc * 16 + col;
  float njxv = nx[colIdx], njyv = ny[colIdx];

  float ab = 0.f, aa = 0.f, bb = 0.f;
  #pragma unroll
  for (int r = 0; r < 4; ++r) {
    int rowLocal = wr * 16 + quad * 4 + r;
    int grow = ti + rowLocal;
    float nix = nx[grow], niy = ny[grow];
    float dxv = sqrtf(fmaxf(nix + njxv - 2.f * accx[r], 0.f) + 1e-12f);
    float dyv = sqrtf(fmaxf(niy + njyv - 2.f * accy[r], 0.f) + 1e-12f);
    ab = fmaf(dxv, dyv, ab); aa = fmaf(dxv, dxv, aa); bb = fmaf(dyv, dyv, bb);
    float rsx = dxv, rsy = dyv;
    #pragma unroll
    for (int o = 8; o > 0; o >>= 1) {
      rsx += __shfl_down(rsx, o, 16);
      rsy += __shfl_down(rsy, o, 16);
    }
    if (col == 0) {
      redR[0][wc][rowLocal] = rsx;
      redR[1][wc][rowLocal] = rsy;
    }
  }

  #pragma unroll
  for (int o = 32; o > 0; o >>= 1) {
    ab += __shfl_down(ab, o, 64);
    aa += __shfl_down(aa, o, 64);
    bb += __shfl_down(bb, o, 64);
  }
  if (lane == 0) { redp[0][w] = ab; redp[1][w] = aa; redp[2][w] = bb; }
  __syncthreads();

  if (tid < 64) {
    float rx = redR[0][0][tid] + redR[0][1][tid] + redR[0][2][tid] + redR[0][3][tid];
    float ry = redR[1][0][tid] + redR[1][1][tid] + redR[1][2][tid] + redR[1][3][tid];
    atomicAdd(&Rx[ti + tid], rx);
    atomicAdd(&Ry[ti + tid], ry);
  } else if (tid >= 64 && tid < 67) {
    int q = tid - 64;
    float s = 0.f;
    #pragma unroll
    for (int i = 0; i < 16; ++i) s += redp[q][i];
    atomicAdd(&sums[q], s);
  }

  // -------- last block finalizes (all cross-block data via device-scope atomics) --
  __threadfence();
  if (tid == 0) done = atomicAdd(counter, 1u);
  __syncthreads();
  if (done != 255) return;

  double rx = (double)atomicAdd(&Rx[tid], 0.0f);   // coherent read, 1024 rows
  double ry = (double)atomicAdd(&Ry[tid], 0.0f);
  double sx = rx, sy = ry, srr = rx * ry, sxx = rx * rx, syy = ry * ry;
  #pragma unroll
  for (int o = 32; o > 0; o >>= 1) {
    sx += __shfl_down(sx, o, 64);  sy += __shfl_down(sy, o, 64);
    srr += __shfl_down(srr, o, 64); sxx += __shfl_down(sxx, o, 64);
    syy += __shfl_down(syy, o, 64);
  }
  __shared__ double td[5][16];
  if (lane == 0) { td[0][w] = sx; td[1][w] = sy; td[2][w] = srr; td[3][w] = sxx; td[4][w] = syy; }
  __syncthreads();
  if (tid == 0) {
    sx = 0; sy = 0; srr = 0; sxx = 0; syy = 0;
    #pragma unroll
    for (int i = 0; i < 16; ++i) {
      sx += td[0][i]; sy += td[1][i]; srr += td[2][i]; sxx += td[3][i]; syy += td[4][i];
    }
    double abt = (double)atomicAdd(&sums[0], 0.0f);
    double aat = (double)atomicAdd(&sums[1], 0.0f);
    double bbt = (double)atomicAdd(&sums[2], 0.0f);
    const double n = (double)NN, n2 = n * n;
    double AB = abt - (2.0 / n) * srr + sx * sy / n2;
    double AA = aat - (2.0 / n) * sxx + sx * sx / n2;
    double BB = bbt - (2.0 / n) * syy + sy * sy / n2;
    double xy = AB / n2, xx = AA / n2, yy = BB / n2;
    double r = xy / sqrt(xx * yy + 1e-9);
    out[0] = (float)(1.0 - r);
  }
}

extern "C" void kernel_launch(void* const* d_in, const int* in_sizes, int n_in,
                              void* d_out, int out_size, void* d_ws, size_t ws_size,
                              hipStream_t stream) {
  const float* in0 = (const float*)d_in[0];   // output_1 (N,T,C) fp32
  const float* in1 = (const float*)d_in[1];   // feature  (N,T,C) fp32

  char* ws = (char*)d_ws;
  const size_t SZ = (size_t)NN * CC * sizeof(ushort);     // 512 KB per bf16 array
  ushort* xh = (ushort*)(ws);
  ushort* xl = (ushort*)(ws + SZ);
  ushort* yh = (ushort*)(ws + 2 * SZ);
  ushort* yl = (ushort*)(ws + 3 * SZ);
  float* nx  = (float*)(ws + 4 * SZ);                      // 4 KB
  float* ny  = (float*)(ws + 4 * SZ + 4096);               // 4 KB
  float* Rx  = (float*)(ws + 4 * SZ + 8192);               // 4 KB (zeroed by k1)
  float* Ry  = (float*)(ws + 4 * SZ + 12288);              // 4 KB (zeroed by k1)
  float* sums = (float*)(ws + 4 * SZ + 16384);             // 3 floats (zeroed by k1)
  unsigned* counter = (unsigned*)(ws + 4 * SZ + 16384 + 64); // 1 uint (zeroed by k1)

  mean_norm_kernel<<<2 * NN, 1024, 0, stream>>>(in0, in1, xh, xl, yh, yl, nx, ny,
                                                Rx, Ry, sums, counter);
  dist_kernel<<<dim3(16, 16), 1024, 0, stream>>>(xh, xl, yh, yl, nx, ny,
                                                 Rx, Ry, sums, counter, (float*)d_out);
}

// Round 7
// 219.161 us; speedup vs baseline: 1.2072x; 1.0179x over previous
//
#include <hip/hip_runtime.h>
#include <math.h>

#define NN 1024
#define CC 256
#define TT 64

typedef __attribute__((ext_vector_type(8))) short bf16x8;  // 8 bf16 (4 VGPRs)
typedef __attribute__((ext_vector_type(4))) float f32x4;   // MFMA accumulator

// Fragment-native layout for each bf16 array:
//   [rowtile rt(64)][ktile kt(8)][lane(64)][j(8)]  (ushort)
//   lane = quad*16 + (row&15), k = kt*32 + quad*8 + j
// => a wave's fragment load for (rt,kt) is 64 lanes x 16 B CONTIGUOUS (1 KB).
#define FRAG_US(rt, kt) (((size_t)(rt) * 8 + (kt)) * 512)   // ushort offset

// round-to-nearest-even fp32 -> bf16 bits
__device__ __forceinline__ ushort f2bf(float f) {
  unsigned u = __float_as_uint(f);
  return (ushort)((u + 0x7fffu + ((u >> 16) & 1u)) >> 16);
}
__device__ __forceinline__ float bf2f(ushort b) {
  return __uint_as_float(((unsigned)b) << 16);
}

// ---------------- kernel 1: time-mean + norms + bf16 hi/lo split ----------------
// 2048 blocks x 1024 threads (16 waves). Block b -> tensor (b>>10), row (b&1023).
// Each thread: 4 independent float4 loads, LDS tree across the 16 waves.
// Writes the bf16 hi/lo arrays in MFMA-fragment-native layout.
__global__ __launch_bounds__(1024) void mean_norm_kernel(
    const float* __restrict__ in0, const float* __restrict__ in1,
    ushort* __restrict__ xh, ushort* __restrict__ xl,
    ushort* __restrict__ yh, ushort* __restrict__ yl,
    float* __restrict__ nx, float* __restrict__ ny,
    float* __restrict__ Rx, float* __restrict__ Ry,
    float* __restrict__ sums, unsigned* __restrict__ counter) {
  int b = blockIdx.x;
  int tid = threadIdx.x;

  // init duties for the fused dist+finalize kernel (runs strictly later)
  if (b == 0) Rx[tid] = 0.f;
  else if (b == 1) Ry[tid] = 0.f;
  else if (b == 2) { if (tid < 3) sums[tid] = 0.f; if (tid == 3) *counter = 0u; }

  int m = b >> 10;
  int n = b & (NN - 1);
  int c4 = tid & 63;            // float4 channel index (64 per row)
  int tq = tid >> 6;            // wave id = time-16th (0..15)
  const float4* src = (const float4*)((m ? in1 : in0) + (size_t)n * (TT * CC)) + c4;

  float4 v0 = src[(tq * 4 + 0) * (CC / 4)];
  float4 v1 = src[(tq * 4 + 1) * (CC / 4)];
  float4 v2 = src[(tq * 4 + 2) * (CC / 4)];
  float4 v3 = src[(tq * 4 + 3) * (CC / 4)];
  float4 s;
  s.x = (v0.x + v1.x) + (v2.x + v3.x);
  s.y = (v0.y + v1.y) + (v2.y + v3.y);
  s.z = (v0.z + v1.z) + (v2.z + v3.z);
  s.w = (v0.w + v1.w) + (v2.w + v3.w);

  __shared__ float4 red[16][64];
  red[tq][c4] = s;
  __syncthreads();

  if (tid < 64) {
    float4 acc = red[0][tid];
    #pragma unroll
    for (int i = 1; i < 16; ++i) {
      float4 t = red[i][tid];
      acc.x += t.x; acc.y += t.y; acc.z += t.z; acc.w += t.w;
    }
    const float inv = 1.0f / TT;
    acc.x *= inv; acc.y *= inv; acc.z *= inv; acc.w *= inv;

    // fragment-native store: channels c = tid*4 .. tid*4+3
    int rt = n >> 4, rl = n & 15;
    int kt = tid >> 3;            // c4>>3
    int quad = (tid >> 1) & 3;
    int lane = quad * 16 + rl;
    int jbase = (tid & 1) * 4;
    size_t idx = FRAG_US(rt, kt) + (size_t)lane * 8 + jbase;

    ushort* ho = m ? yh : xh;
    ushort* lo = m ? yl : xl;
    ushort4 h4, l4;
    h4.x = f2bf(acc.x); l4.x = f2bf(acc.x - bf2f(h4.x));
    h4.y = f2bf(acc.y); l4.y = f2bf(acc.y - bf2f(h4.y));
    h4.z = f2bf(acc.z); l4.z = f2bf(acc.z - bf2f(h4.z));
    h4.w = f2bf(acc.w); l4.w = f2bf(acc.w - bf2f(h4.w));
    *(ushort4*)(ho + idx) = h4;
    *(ushort4*)(lo + idx) = l4;

    float ssq = fmaf(acc.x, acc.x, fmaf(acc.y, acc.y, fmaf(acc.z, acc.z, acc.w * acc.w)));
    #pragma unroll
    for (int o = 32; o > 0; o >>= 1) ssq += __shfl_down(ssq, o, 64);
    if (tid == 0) (m ? ny : nx)[n] = ssq;
  }
}

// ---------------- kernel 2: MFMA gram from fragment-native L2 + finalize ----------
// Grid (32,16) = 512 blocks x 512 threads (8 waves; 2 blocks/CU, 16 waves/CU).
// Block tile 64 rows x 32 cols; wave w -> subtile (wr=w>>1, wc=w&1) of 16x16.
// Per ktile: 8 contiguous 1 KB fragment loads (L1/L2-resident) + 6 MFMAs.
// No LDS in the K-loop; intra-block redundant loads hit L1.
__global__ __launch_bounds__(512, 4) void dist_kernel(
    const ushort* __restrict__ xh, const ushort* __restrict__ xl,
    const ushort* __restrict__ yh, const ushort* __restrict__ yl,
    const float* __restrict__ nx, const float* __restrict__ ny,
    float* __restrict__ Rx, float* __restrict__ Ry,
    float* __restrict__ sums, unsigned* __restrict__ counter,
    float* __restrict__ out) {
  int tid = threadIdx.x;
  int lane = tid & 63;
  int w = tid >> 6;              // wave 0..7
  int wr = w >> 1, wc = w & 1;
  int col = lane & 15, quad = lane >> 4;

  int rtA = blockIdx.y * 4 + wr;   // A rowtile (0..63)
  int rtB = blockIdx.x * 2 + wc;   // B rowtile (0..63)
  size_t la = (size_t)lane * 8;

  const ushort* pAhx = xh + FRAG_US(rtA, 0) + la;
  const ushort* pAlx = xl + FRAG_US(rtA, 0) + la;
  const ushort* pAhy = yh + FRAG_US(rtA, 0) + la;
  const ushort* pAly = yl + FRAG_US(rtA, 0) + la;
  const ushort* pBhx = xh + FRAG_US(rtB, 0) + la;
  const ushort* pBlx = xl + FRAG_US(rtB, 0) + la;
  const ushort* pBhy = yh + FRAG_US(rtB, 0) + la;
  const ushort* pBly = yl + FRAG_US(rtB, 0) + la;

  f32x4 accx = {};
  f32x4 accy = {};

  #pragma unroll 2
  for (int kt = 0; kt < 8; ++kt) {
    size_t o = (size_t)kt * 512;                 // ushorts per ktile step
    bf16x8 Ahx = *(const bf16x8*)(pAhx + o);
    bf16x8 Alx = *(const bf16x8*)(pAlx + o);
    bf16x8 Ahy = *(const bf16x8*)(pAhy + o);
    bf16x8 Aly = *(const bf16x8*)(pAly + o);
    bf16x8 Bhx = *(const bf16x8*)(pBhx + o);
    bf16x8 Blx = *(const bf16x8*)(pBlx + o);
    bf16x8 Bhy = *(const bf16x8*)(pBhy + o);
    bf16x8 Bly = *(const bf16x8*)(pBly + o);
    accx = __builtin_amdgcn_mfma_f32_16x16x32_bf16(Ahx, Bhx, accx, 0, 0, 0);
    accx = __builtin_amdgcn_mfma_f32_16x16x32_bf16(Ahx, Blx, accx, 0, 0, 0);
    accx = __builtin_amdgcn_mfma_f32_16x16x32_bf16(Alx, Bhx, accx, 0, 0, 0);
    accy = __builtin_amdgcn_mfma_f32_16x16x32_bf16(Ahy, Bhy, accy, 0, 0, 0);
    accy = __builtin_amdgcn_mfma_f32_16x16x32_bf16(Ahy, Bly, accy, 0, 0, 0);
    accy = __builtin_amdgcn_mfma_f32_16x16x32_bf16(Aly, Bhy, accy, 0, 0, 0);
  }

  // ---- epilogue: d = sqrt(max(ni+nj-2g,0)+1e-12); row sums + product sums ----
  // C/D map: col = lane&15, row = quad*4 + reg
  int ti = blockIdx.y * 64, tj = blockIdx.x * 32;
  int colIdx = tj + wc * 16 + col;
  float njxv = nx[colIdx], njyv = ny[colIdx];

  __shared__ float redR[2][2][64];   // [x/y][wc][rowLocal]
  __shared__ float redp[3][8];       // ab/aa/bb per wave
  __shared__ unsigned done;

  float ab = 0.f, aa = 0.f, bb = 0.f;
  #pragma unroll
  for (int r = 0; r < 4; ++r) {
    int rowLocal = wr * 16 + quad * 4 + r;
    int grow = ti + rowLocal;
    float nix = nx[grow], niy = ny[grow];
    float dxv = sqrtf(fmaxf(nix + njxv - 2.f * accx[r], 0.f) + 1e-12f);
    float dyv = sqrtf(fmaxf(niy + njyv - 2.f * accy[r], 0.f) + 1e-12f);
    ab = fmaf(dxv, dyv, ab); aa = fmaf(dxv, dxv, aa); bb = fmaf(dyv, dyv, bb);
    float rsx = dxv, rsy = dyv;
    #pragma unroll
    for (int o = 8; o > 0; o >>= 1) {
      rsx += __shfl_down(rsx, o, 16);
      rsy += __shfl_down(rsy, o, 16);
    }
    if (col == 0) {
      redR[0][wc][rowLocal] = rsx;
      redR[1][wc][rowLocal] = rsy;
    }
  }

  #pragma unroll
  for (int o = 32; o > 0; o >>= 1) {
    ab += __shfl_down(ab, o, 64);
    aa += __shfl_down(aa, o, 64);
    bb += __shfl_down(bb, o, 64);
  }
  if (lane == 0) { redp[0][w] = ab; redp[1][w] = aa; redp[2][w] = bb; }
  __syncthreads();

  if (tid < 64) {
    float rx = redR[0][0][tid] + redR[0][1][tid];
    float ry = redR[1][0][tid] + redR[1][1][tid];
    atomicAdd(&Rx[ti + tid], rx);
    atomicAdd(&Ry[ti + tid], ry);
  } else if (tid >= 64 && tid < 67) {
    int q = tid - 64;
    float s = 0.f;
    #pragma unroll
    for (int i = 0; i < 8; ++i) s += redp[q][i];
    atomicAdd(&sums[q], s);
  }

  // -------- last block finalizes (cross-block data via device-scope atomics) -----
  __threadfence();
  if (tid == 0) done = atomicAdd(counter, 1u);
  __syncthreads();
  if (done != 511) return;

  double sx = 0, sy = 0, srr = 0, sxx = 0, syy = 0;
  #pragma unroll
  for (int i = 0; i < 2; ++i) {
    int row = tid + i * 512;
    double rx = (double)atomicAdd(&Rx[row], 0.0f);   // coherent read
    double ry = (double)atomicAdd(&Ry[row], 0.0f);
    sx += rx; sy += ry; srr += rx * ry; sxx += rx * rx; syy += ry * ry;
  }
  #pragma unroll
  for (int o = 32; o > 0; o >>= 1) {
    sx += __shfl_down(sx, o, 64);  sy += __shfl_down(sy, o, 64);
    srr += __shfl_down(srr, o, 64); sxx += __shfl_down(sxx, o, 64);
    syy += __shfl_down(syy, o, 64);
  }
  __shared__ double td[5][8];
  if (lane == 0) { td[0][w] = sx; td[1][w] = sy; td[2][w] = srr; td[3][w] = sxx; td[4][w] = syy; }
  __syncthreads();
  if (tid == 0) {
    sx = 0; sy = 0; srr = 0; sxx = 0; syy = 0;
    #pragma unroll
    for (int i = 0; i < 8; ++i) {
      sx += td[0][i]; sy += td[1][i]; srr += td[2][i]; sxx += td[3][i]; syy += td[4][i];
    }
    double abt = (double)atomicAdd(&sums[0], 0.0f);
    double aat = (double)atomicAdd(&sums[1], 0.0f);
    double bbt = (double)atomicAdd(&sums[2], 0.0f);
    const double n = (double)NN, n2 = n * n;
    double AB = abt - (2.0 / n) * srr + sx * sy / n2;
    double AA = aat - (2.0 / n) * sxx + sx * sx / n2;
    double BB = bbt - (2.0 / n) * syy + sy * sy / n2;
    double xy = AB / n2, xx = AA / n2, yy = BB / n2;
    double r = xy / sqrt(xx * yy + 1e-9);
    out[0] = (float)(1.0 - r);
  }
}

extern "C" void kernel_launch(void* const* d_in, const int* in_sizes, int n_in,
                              void* d_out, int out_size, void* d_ws, size_t ws_size,
                              hipStream_t stream) {
  const float* in0 = (const float*)d_in[0];   // output_1 (N,T,C) fp32
  const float* in1 = (const float*)d_in[1];   // feature  (N,T,C) fp32

  char* ws = (char*)d_ws;
  const size_t SZ = (size_t)NN * CC * sizeof(ushort);     // 512 KB per bf16 array
  ushort* xh = (ushort*)(ws);
  ushort* xl = (ushort*)(ws + SZ);
  ushort* yh = (ushort*)(ws + 2 * SZ);
  ushort* yl = (ushort*)(ws + 3 * SZ);
  float* nx  = (float*)(ws + 4 * SZ);                      // 4 KB
  float* ny  = (float*)(ws + 4 * SZ + 4096);               // 4 KB
  float* Rx  = (float*)(ws + 4 * SZ + 8192);               // 4 KB (zeroed by k1)
  float* Ry  = (float*)(ws + 4 * SZ + 12288);              // 4 KB (zeroed by k1)
  float* sums = (float*)(ws + 4 * SZ + 16384);             // 3 floats (zeroed by k1)
  unsigned* counter = (unsigned*)(ws + 4 * SZ + 16384 + 64); // 1 uint (zeroed by k1)

  mean_norm_kernel<<<2 * NN, 1024, 0, stream>>>(in0, in1, xh, xl, yh, yl, nx, ny,
                                                Rx, Ry, sums, counter);
  dist_kernel<<<dim3(32, 16), 512, 0, stream>>>(xh, xl, yh, yl, nx, ny,
                                                Rx, Ry, sums, counter, (float*)d_out);
}